// Round 4
// baseline (222.579 us; speedup 1.0000x reference)
//
#include <hip/hip_runtime.h>

// ============================================================================
// ESupConLoss on MI355X (gfx950)
//
// out = ( pt_loss + sum_i[ -pos_i + neg_i + 2*dot(au_i,tp_i) ] ) / (N+2)
//   pos_i = ln( sum_{j!=i} e^{au_i.au_j} + e^{tp_i.tp_j} )
//   neg_i = ln( sum_{j!=i} e^{au_i.tp_j} )
//   pt_loss = (sum_i au_i - sum_i tp_i) . (pt1 - pt0) / N
//
// log2-domain trick: inputs pre-scaled by sqrt(log2 e), cast bf16; MFMA dots
// are log2-domain, v_exp_f32 (=2^x) needs no scaling. Shift C2=32 folded into
// MFMA C-init, cancels in -pos+neg.
//
// Round-4: BARRIER-FREE score kernel. Rounds 1-3 all plateaued at ~65 us with
// all pipes ~30% busy: the 2-barrier-per-tile structure phase-locks every
// resident wave (exp burst / MFMA burst / drain together), so pipes never
// overlap. B-panel working set is L1/L2-resident (whole dataset = 4 MiB bf16),
// so LDS broadcast isn't worth the barriers: load B fragments directly from
// global per wave (each wave64 dwordx4 touches exactly 16 x 64B lines, zero
// over-fetch), no __syncthreads anywhere, waves drift freely.
// ============================================================================

typedef float f32x4 __attribute__((ext_vector_type(4)));
typedef __bf16 bf16x8 __attribute__((ext_vector_type(8)));

static constexpr int   N_ROWS = 8192;
static constexpr int   DIM    = 128;
static constexpr float SQRT_LOG2E = 1.2011224087864498f; // sqrt(log2(e))
static constexpr float C2  = 32.0f;                      // log2-domain shift
static constexpr float LN2 = 0.6931471805599453f;

// ---------------- ws layout (bytes) ----------------
// zb_au : bf16[8192*128]  @ 0          (2 MiB)
// zb_tp : bf16[8192*128]  @ 2097152    (2 MiB)
// P     : f32[8192]       @ 4194304
// Ng    : f32[8192]       @ 4227072
// acc   : f32[2]          @ 4259840
// done  : u32             @ 4259848

__device__ inline unsigned short f2bf_rne(float x) {
    unsigned u = __builtin_bit_cast(unsigned, x);
    u += 0x7fffu + ((u >> 16) & 1u);
    return (unsigned short)(u >> 16);
}

// ---------------------------------------------------------------------------
// Kernel 1: convert f32 -> bf16 (scaled), zero P/Ng/acc/done.
// ---------------------------------------------------------------------------
__global__ void prep_kernel(const float* __restrict__ zau,
                            const float* __restrict__ ztp,
                            unsigned short* __restrict__ bau,
                            unsigned short* __restrict__ btp,
                            float* __restrict__ P, float* __restrict__ Ng,
                            float* __restrict__ acc, unsigned* __restrict__ done) {
    int gid  = blockIdx.x * blockDim.x + threadIdx.x;   // 0..262143
    int base = gid * 4;
    float4 a = *reinterpret_cast<const float4*>(zau + base);
    float4 t = *reinterpret_cast<const float4*>(ztp + base);
    ushort4 ua, ut;
    ua.x = f2bf_rne(a.x * SQRT_LOG2E); ua.y = f2bf_rne(a.y * SQRT_LOG2E);
    ua.z = f2bf_rne(a.z * SQRT_LOG2E); ua.w = f2bf_rne(a.w * SQRT_LOG2E);
    ut.x = f2bf_rne(t.x * SQRT_LOG2E); ut.y = f2bf_rne(t.y * SQRT_LOG2E);
    ut.z = f2bf_rne(t.z * SQRT_LOG2E); ut.w = f2bf_rne(t.w * SQRT_LOG2E);
    *reinterpret_cast<ushort4*>(bau + base) = ua;
    *reinterpret_cast<ushort4*>(btp + base) = ut;
    if (gid < N_ROWS) { P[gid] = 0.0f; Ng[gid] = 0.0f; }
    if (gid == 0)     { acc[0] = 0.0f; acc[1] = 0.0f; done[0] = 0u; }
}

// ---------------------------------------------------------------------------
// Kernel 2. Grid 1024 = 16 col-splits (slow) x 64 row-tiles (fast).
// Block = 4 waves, wave owns 32 rows, iterates 16 col-tiles of 32 cols.
// NO LDS, NO BARRIERS: B fragments loaded per-wave from global (L1/L2 hit).
// Per-lane B address (m89-verified layout, same pattern as A-frag loads that
// have passed 3 rounds at absmax 0):
//   elem j of lane -> col n = (lane&15), k = (lane>>4)*8 + j
//   byte addr = (colbase + nt*16 + l15)*256 + k_outer*64 + quad*16
//   -> the 4 quads of one l15 share one 64B line: 16 lines/wave-load, exact.
// C/D: reg r of lane -> row (lane>>4)*4 + r, col (lane&15)
// ---------------------------------------------------------------------------
template<bool DIAG>
__device__ inline void expacc(const f32x4 (&a)[2][2], float (&dst)[2][4],
                              int r0w, int colp, int quad, int l15) {
#pragma unroll
    for (int mt = 0; mt < 2; mt++)
#pragma unroll
        for (int nt = 0; nt < 2; nt++)
#pragma unroll
            for (int r = 0; r < 4; r++) {
                float e = __builtin_amdgcn_exp2f(a[mt][nt][r]);
                if (DIAG) {
                    int grow = r0w + mt * 16 + quad * 4 + r;
                    int gcol = colp + nt * 16 + l15;
                    if (grow == gcol) e = 0.0f;
                }
                dst[mt][r] += e;
            }
}

__global__ __launch_bounds__(256, 3)
void score_kernel(const unsigned short* __restrict__ bau,
                  const unsigned short* __restrict__ btp,
                  float* __restrict__ P, float* __restrict__ Ng) {
    const int tid  = threadIdx.x;
    const int lane = tid & 63;
    const int wave = tid >> 6;
    const int quad = lane >> 4;
    const int l15  = lane & 15;
    const int rb   = blockIdx.x & 63;   // row tile (fast index)
    const int cs   = blockIdx.x >> 6;   // col split (slow index)
    const int r0w  = rb * 128 + wave * 32;

    // loop-invariant A fragments (rows of au / tp), 64 VGPRs
    bf16x8 aAu[2][4], aTp[2][4];
#pragma unroll
    for (int mt = 0; mt < 2; mt++) {
        int row = r0w + mt * 16 + l15;
        const unsigned short* pa = bau + row * DIM + quad * 8;
        const unsigned short* pt = btp + row * DIM + quad * 8;
#pragma unroll
        for (int k = 0; k < 4; k++) {
            aAu[mt][k] = *reinterpret_cast<const bf16x8*>(pa + k * 32);
            aTp[mt][k] = *reinterpret_cast<const bf16x8*>(pt + k * 32);
        }
    }

    float sP[2][4] = {{0.f,0.f,0.f,0.f},{0.f,0.f,0.f,0.f}};
    float sN[2][4] = {{0.f,0.f,0.f,0.f},{0.f,0.f,0.f,0.f}};

    // per-lane element offset inside the column panel
    const int laneElem = l15 * DIM + quad * 8;
    const unsigned short* panAu = bau + (size_t)cs * 512 * DIM + laneElem;
    const unsigned short* panTp = btp + (size_t)cs * 512 * DIM + laneElem;

    for (int ct = 0; ct < 16; ct++) {
        const int colbase = cs * 512 + ct * 32;
        const unsigned short* pa = panAu + ct * 32 * DIM;
        const unsigned short* pt = panTp + ct * 32 * DIM;
        const bool diag = (colbase < r0w + 32) && (colbase + 32 > r0w);

        // ---- load au B-fragments (8 x dwordx4), MFMA s_aa ----
        bf16x8 bA[2][4];
#pragma unroll
        for (int nt = 0; nt < 2; nt++)
#pragma unroll
            for (int k = 0; k < 4; k++)
                bA[nt][k] = *reinterpret_cast<const bf16x8*>(
                    pa + nt * 16 * DIM + k * 32);

        f32x4 accA[2][2];
#pragma unroll
        for (int mt = 0; mt < 2; mt++)
#pragma unroll
            for (int nt = 0; nt < 2; nt++)
                accA[mt][nt] = f32x4{-C2, -C2, -C2, -C2};
#pragma unroll
        for (int k = 0; k < 4; k++)
#pragma unroll
            for (int mt = 0; mt < 2; mt++) {
                accA[mt][0] = __builtin_amdgcn_mfma_f32_16x16x32_bf16(
                    aAu[mt][k], bA[0][k], accA[mt][0], 0, 0, 0);
                accA[mt][1] = __builtin_amdgcn_mfma_f32_16x16x32_bf16(
                    aAu[mt][k], bA[1][k], accA[mt][1], 0, 0, 0);
            }

        // ---- load tp B-fragments (independent; overlaps exp below) ----
        bf16x8 bT[2][4];
#pragma unroll
        for (int nt = 0; nt < 2; nt++)
#pragma unroll
            for (int k = 0; k < 4; k++)
                bT[nt][k] = *reinterpret_cast<const bf16x8*>(
                    pt + nt * 16 * DIM + k * 32);

        // ---- exp s_aa ----
        if (diag) expacc<true >(accA, sP, r0w, colbase, quad, l15);
        else      expacc<false>(accA, sP, r0w, colbase, quad, l15);

        // ---- MFMA s_tt and s_at (shared tp fragments) ----
        f32x4 accT[2][2], accX[2][2];
#pragma unroll
        for (int mt = 0; mt < 2; mt++)
#pragma unroll
            for (int nt = 0; nt < 2; nt++) {
                accT[mt][nt] = f32x4{-C2, -C2, -C2, -C2};
                accX[mt][nt] = f32x4{-C2, -C2, -C2, -C2};
            }
#pragma unroll
        for (int k = 0; k < 4; k++)
#pragma unroll
            for (int mt = 0; mt < 2; mt++) {
                accT[mt][0] = __builtin_amdgcn_mfma_f32_16x16x32_bf16(
                    aTp[mt][k], bT[0][k], accT[mt][0], 0, 0, 0);
                accX[mt][0] = __builtin_amdgcn_mfma_f32_16x16x32_bf16(
                    aAu[mt][k], bT[0][k], accX[mt][0], 0, 0, 0);
                accT[mt][1] = __builtin_amdgcn_mfma_f32_16x16x32_bf16(
                    aTp[mt][k], bT[1][k], accT[mt][1], 0, 0, 0);
                accX[mt][1] = __builtin_amdgcn_mfma_f32_16x16x32_bf16(
                    aAu[mt][k], bT[1][k], accX[mt][1], 0, 0, 0);
            }

        // ---- exp s_tt, s_at ----
        if (diag) { expacc<true >(accT, sP, r0w, colbase, quad, l15);
                    expacc<true >(accX, sN, r0w, colbase, quad, l15); }
        else      { expacc<false>(accT, sP, r0w, colbase, quad, l15);
                    expacc<false>(accX, sN, r0w, colbase, quad, l15); }
    }

    // ---- reduce across the 16 lanes of each quad, one atomic per row ----
#pragma unroll
    for (int mt = 0; mt < 2; mt++)
#pragma unroll
        for (int r = 0; r < 4; r++) {
            float p = sP[mt][r], ng = sN[mt][r];
            for (int m = 1; m < 16; m <<= 1) {
                p  += __shfl_xor(p,  m, 64);
                ng += __shfl_xor(ng, m, 64);
            }
            if (l15 == 0) {
                int row = r0w + mt * 16 + quad * 4 + r;
                atomicAdd(&P[row],  p);
                atomicAdd(&Ng[row], ng);
            }
        }
}

// ---------------------------------------------------------------------------
// Kernel 3: per-row  ln2*(log2 Ng - log2 P) + 2*dot(au_i,tp_i), plus the
// pt numerator. Last finishing block writes the final scalar.
// ---------------------------------------------------------------------------
__global__ void finalize_kernel(const float* __restrict__ zau,
                                const float* __restrict__ ztp,
                                const float* __restrict__ fc,
                                const float* __restrict__ P,
                                const float* __restrict__ Ng,
                                float* __restrict__ acc,
                                unsigned* __restrict__ done,
                                float* __restrict__ out) {
    int tid     = threadIdx.x;
    int lane    = tid & 63;
    int wave_id = blockIdx.x * 4 + (tid >> 6);   // 0..1023

    float2 w0 = *reinterpret_cast<const float2*>(fc + 2 * lane);        // pt0
    float2 w1 = *reinterpret_cast<const float2*>(fc + 256 + 2 * lane);  // pt1
    float wx = w1.x - w0.x, wy = w1.y - w0.y;

    float ptp = 0.0f, ssum = 0.0f;
    for (int j = 0; j < 8; j++) {
        int i = wave_id * 8 + j;
        float2 a = *reinterpret_cast<const float2*>(zau + i * DIM + 2 * lane);
        float2 t = *reinterpret_cast<const float2*>(ztp + i * DIM + 2 * lane);
        float d = a.x * t.x + a.y * t.y;
        ptp += (a.x - t.x) * wx + (a.y - t.y) * wy;
        for (int m = 1; m < 64; m <<= 1) d += __shfl_xor(d, m, 64);
        if (lane == 0) {
            float c = LN2 * (__builtin_amdgcn_logf(Ng[i]) -
                             __builtin_amdgcn_logf(P[i])) + 2.0f * d;
            ssum += c;
        }
    }
    for (int m = 1; m < 64; m <<= 1) ptp += __shfl_xor(ptp, m, 64);
    if (lane == 0) {
        atomicAdd(&acc[0], ssum);
        atomicAdd(&acc[1], ptp);
    }

    __syncthreads();
    if (tid == 0) {
        __threadfence();
        unsigned ticket = atomicAdd(done, 1u);
        if (ticket == gridDim.x - 1) {
            float a0 = atomicAdd(&acc[0], 0.0f);   // coherent read
            float a1 = atomicAdd(&acc[1], 0.0f);
            out[0] = (a1 / (float)N_ROWS + a0) / (float)(N_ROWS + 2);
        }
    }
}

extern "C" void kernel_launch(void* const* d_in, const int* in_sizes, int n_in,
                              void* d_out, int out_size, void* d_ws, size_t ws_size,
                              hipStream_t stream) {
    const float* zau = (const float*)d_in[0];
    const float* ztp = (const float*)d_in[1];
    const float* fc  = (const float*)d_in[2];
    // d_in[3] = labels (unused by the math)
    float* out = (float*)d_out;

    char* ws = (char*)d_ws;
    unsigned short* bau = (unsigned short*)(ws);
    unsigned short* btp = (unsigned short*)(ws + 2097152);
    float*    P    = (float*)(ws + 4194304);
    float*    Ng   = (float*)(ws + 4227072);
    float*    acc  = (float*)(ws + 4259840);
    unsigned* done = (unsigned*)(ws + 4259848);

    prep_kernel<<<dim3(1024), dim3(256), 0, stream>>>(zau, ztp, bau, btp, P, Ng, acc, done);
    score_kernel<<<dim3(1024), dim3(256), 0, stream>>>(bau, btp, P, Ng);
    finalize_kernel<<<dim3(256), dim3(256), 0, stream>>>(zau, ztp, fc, P, Ng, acc, done, out);
}

// Round 5
// 209.690 us; speedup vs baseline: 1.0615x; 1.0615x over previous
//
#include <hip/hip_runtime.h>
#include <math.h>

// ============================================================================
// ESupConLoss on MI355X (gfx950) — round 5: symmetry-halved aa/tt.
//
// out = ( pt_loss + sum_i[ -pos_i + neg_i + 2*dot(au_i,tp_i) ] ) / (N+2)
//   P[i]  = sum_{j!=i} e^{au_i.au_j} + e^{tp_i.tp_j}   (pos = ln P)
//   Ng[i] = sum_{j!=i} e^{au_i.tp_j}                   (neg = ln Ng)
//
// aa/tt are SYMMETRIC: exp-row-sums == exp-col-sums. S-pass computes only
// upper-triangle 128x128 tile pairs (ti<=tj, 2080 blocks); off-diag tiles
// scatter row sums to P[ti-rows] AND col sums to P[tj-rows]  => 1/3 less
// MFMA+exp work overall. X-pass (1024 blocks) = round-3's verified at-sweep.
// Both fused in one 3104-block launch; last block (done ticket) reduces the
// final scalar. prep computes bf16 cast + diag dots dd[i] + pt partials.
//
// log2-domain trick: inputs pre-scaled by sqrt(log2 e) -> MFMA dots are
// log2-domain, v_exp_f32 (=2^x) needs no scaling; shift C2=32 in C-init
// cancels in -pos+neg.
// ============================================================================

typedef float f32x4 __attribute__((ext_vector_type(4)));
typedef __bf16 bf16x8 __attribute__((ext_vector_type(8)));

static constexpr int   N_ROWS = 8192;
static constexpr int   DIM    = 128;
static constexpr float SQRT_LOG2E = 1.2011224087864498f; // sqrt(log2(e))
static constexpr float C2  = 32.0f;                      // log2-domain shift
static constexpr float LN2 = 0.6931471805599453f;
static constexpr int   NS = 2080;   // 64*65/2 symmetric tile-pair blocks
static constexpr int   NX = 1024;   // 64 row-tiles x 16 col-splits (at pass)

// ---------------- ws layout (bytes) ----------------
// bau    : bf16[8192*128] @ 0
// btp    : bf16[8192*128] @ 2097152
// P      : f32[8192]      @ 4194304
// Ng     : f32[8192]      @ 4227072
// dd     : f32[8192]      @ 4259840   (au_i . tp_i, f32 precision)
// ptpart : f32[1024]      @ 4292608   (per-prep-block pt partials)
// done   : u32            @ 4296704

__device__ inline unsigned short f2bf_rne(float x) {
    unsigned u = __builtin_bit_cast(unsigned, x);
    u += 0x7fffu + ((u >> 16) & 1u);
    return (unsigned short)(u >> 16);
}

#define GLD16(gptr, lptr)                                                  \
    __builtin_amdgcn_global_load_lds(                                      \
        (const __attribute__((address_space(1))) void*)(gptr),             \
        (__attribute__((address_space(3))) void*)(lptr), 16, 0, 0)

// ---------------------------------------------------------------------------
// Kernel 1: bf16 convert + dd[i] + pt partials + zero P/Ng/done.
// 1024 blocks x 256. Thread gid handles elems [gid*4, gid*4+4) (= quarter of
// a 128-elem row segment: row = gid>>5, seg = gid&31).
// ---------------------------------------------------------------------------
__global__ void prep_kernel(const float* __restrict__ zau,
                            const float* __restrict__ ztp,
                            const float* __restrict__ fc,
                            unsigned short* __restrict__ bau,
                            unsigned short* __restrict__ btp,
                            float* __restrict__ P, float* __restrict__ Ng,
                            float* __restrict__ dd, float* __restrict__ ptpart,
                            unsigned* __restrict__ done) {
    __shared__ float pw[4];
    const int tid  = threadIdx.x;
    const int gid  = blockIdx.x * 256 + tid;
    const int lane = tid & 63;
    const int base = gid * 4;
    const int seg  = gid & 31;

    float4 a = *reinterpret_cast<const float4*>(zau + base);
    float4 t = *reinterpret_cast<const float4*>(ztp + base);

    ushort4 ua, ut;
    ua.x = f2bf_rne(a.x * SQRT_LOG2E); ua.y = f2bf_rne(a.y * SQRT_LOG2E);
    ua.z = f2bf_rne(a.z * SQRT_LOG2E); ua.w = f2bf_rne(a.w * SQRT_LOG2E);
    ut.x = f2bf_rne(t.x * SQRT_LOG2E); ut.y = f2bf_rne(t.y * SQRT_LOG2E);
    ut.z = f2bf_rne(t.z * SQRT_LOG2E); ut.w = f2bf_rne(t.w * SQRT_LOG2E);
    *reinterpret_cast<ushort4*>(bau + base) = ua;
    *reinterpret_cast<ushort4*>(btp + base) = ut;

    // dd[row] = au_row . tp_row  (32 threads per row -> reduce within 32)
    float d = a.x * t.x + a.y * t.y + a.z * t.z + a.w * t.w;
    d += __shfl_xor(d, 1, 64);  d += __shfl_xor(d, 2, 64);
    d += __shfl_xor(d, 4, 64);  d += __shfl_xor(d, 8, 64);
    d += __shfl_xor(d, 16, 64);
    if ((lane & 31) == 0) dd[gid >> 5] = d;

    // pt partial: (a - t) . (pt1 - pt0) restricted to this thread's 4 dims
    float4 w0 = *reinterpret_cast<const float4*>(fc + seg * 4);
    float4 w1 = *reinterpret_cast<const float4*>(fc + DIM + seg * 4);
    float ptp = (a.x - t.x) * (w1.x - w0.x) + (a.y - t.y) * (w1.y - w0.y)
              + (a.z - t.z) * (w1.z - w0.z) + (a.w - t.w) * (w1.w - w0.w);
    for (int m = 1; m < 64; m <<= 1) ptp += __shfl_xor(ptp, m, 64);
    if (lane == 0) pw[tid >> 6] = ptp;
    __syncthreads();
    if (tid == 0) ptpart[blockIdx.x] = pw[0] + pw[1] + pw[2] + pw[3];

    if (gid < N_ROWS) { P[gid] = 0.0f; Ng[gid] = 0.0f; }
    if (gid == 0)     { done[0] = 0u; }
}

// ---------------------------------------------------------------------------
// Kernel 2: fused S-pass (aa/tt upper triangle) + X-pass (at full) + finale.
// Block = 4 waves; wave owns 32 A-rows. LDS fragment order (verified r2/r3):
//   frag block f (1 KiB) at ushort offset f*512; lane slot = lane*16B.
//   B-frag (nt,k): lane(quad,l15) <- row (colbase+nt*16+l15), elems
//   k*32+quad*8..+8  == MFMA B layout (col=l15, k=quad*8+j).
// C/D: reg r of lane -> row (lane>>4)*4 + r, col (lane&15).
// ---------------------------------------------------------------------------
__global__ __launch_bounds__(256, 3)
void score_kernel(const unsigned short* __restrict__ bau,
                  const unsigned short* __restrict__ btp,
                  float* __restrict__ P, float* __restrict__ Ng,
                  const float* __restrict__ dd,
                  const float* __restrict__ ptpart,
                  unsigned* __restrict__ done,
                  float* __restrict__ out) {
    __shared__ __align__(16) unsigned short lds[16 * 512];   // 16 KiB
    __shared__ float red[4], red2[4];
    __shared__ int lastflag;

    const int tid  = threadIdx.x;
    const int lane = tid & 63;
    const int wave = tid >> 6;
    const int quad = lane >> 4;
    const int l15  = lane & 15;
    const int b    = blockIdx.x;
    const int laneoff = l15 * 256 + quad * 16;   // per-lane global byte offset

    if (b < NS) {
        // ---------------- S-pass: aa/tt tile pair (ti <= tj) ----------------
        // decode upper-triangle index: off(t) = 64t - t(t-1)/2
        int ti = (int)((129.0 - sqrt(16641.0 - 8.0 * (double)b)) * 0.5);
        if (ti < 0) ti = 0;
        while (64 * (ti + 1) - ((ti + 1) * ti) / 2 <= b) ti++;
        while (64 * ti - (ti * (ti - 1)) / 2 > b) ti--;
        const int tj = ti + (b - (64 * ti - (ti * (ti - 1)) / 2));

        const int r0w = ti * 128 + wave * 32;

        bf16x8 aAu[2][4], aTp[2][4];
#pragma unroll
        for (int mt = 0; mt < 2; mt++) {
            int row = r0w + mt * 16 + l15;
            const unsigned short* pa = bau + row * DIM + quad * 8;
            const unsigned short* pt = btp + row * DIM + quad * 8;
#pragma unroll
            for (int k = 0; k < 4; k++) {
                aAu[mt][k] = *reinterpret_cast<const bf16x8*>(pa + k * 32);
                aTp[mt][k] = *reinterpret_cast<const bf16x8*>(pt + k * 32);
            }
        }

        float sP[2][4] = {{0.f,0.f,0.f,0.f},{0.f,0.f,0.f,0.f}};

        for (int ct = 0; ct < 4; ct++) {
            const int colbase = tj * 128 + ct * 32;
            __syncthreads();
#pragma unroll
            for (int j = 0; j < 4; j++) {
                const int f   = wave * 4 + j;      // 0..15
                const int arr = f >> 3;
                const int nt  = (f >> 2) & 1;
                const int k   = f & 3;
                const char* gb = (const char*)(arr ? btp : bau)
                               + ((size_t)(colbase + nt * 16) << 8) + (k << 6);
                GLD16(gb + laneoff, lds + (f << 9));
            }
            __syncthreads();

            bf16x8 bA[2][4], bT[2][4];
#pragma unroll
            for (int nt = 0; nt < 2; nt++)
#pragma unroll
                for (int k = 0; k < 4; k++) {
                    bA[nt][k] = *reinterpret_cast<const bf16x8*>(
                        lds + ((nt * 4 + k) << 9) + lane * 8);
                    bT[nt][k] = *reinterpret_cast<const bf16x8*>(
                        lds + ((8 + nt * 4 + k) << 9) + lane * 8);
                }

            f32x4 accA[2][2], accT[2][2];
#pragma unroll
            for (int mt = 0; mt < 2; mt++)
#pragma unroll
                for (int nt = 0; nt < 2; nt++) {
                    accA[mt][nt] = f32x4{-C2, -C2, -C2, -C2};
                    accT[mt][nt] = f32x4{-C2, -C2, -C2, -C2};
                }
#pragma unroll
            for (int k = 0; k < 4; k++)
#pragma unroll
                for (int mt = 0; mt < 2; mt++) {
                    accA[mt][0] = __builtin_amdgcn_mfma_f32_16x16x32_bf16(
                        aAu[mt][k], bA[0][k], accA[mt][0], 0, 0, 0);
                    accA[mt][1] = __builtin_amdgcn_mfma_f32_16x16x32_bf16(
                        aAu[mt][k], bA[1][k], accA[mt][1], 0, 0, 0);
                    accT[mt][0] = __builtin_amdgcn_mfma_f32_16x16x32_bf16(
                        aTp[mt][k], bT[0][k], accT[mt][0], 0, 0, 0);
                    accT[mt][1] = __builtin_amdgcn_mfma_f32_16x16x32_bf16(
                        aTp[mt][k], bT[1][k], accT[mt][1], 0, 0, 0);
                }

            const bool dg = (colbase < r0w + 32) && (colbase + 32 > r0w);
            float cp0 = 0.f, cp1 = 0.f;
#pragma unroll
            for (int mt = 0; mt < 2; mt++)
#pragma unroll
                for (int nt = 0; nt < 2; nt++)
#pragma unroll
                    for (int r = 0; r < 4; r++) {
                        float eA = __builtin_amdgcn_exp2f(accA[mt][nt][r]);
                        float eT = __builtin_amdgcn_exp2f(accT[mt][nt][r]);
                        if (dg) {
                            int grow = r0w + mt * 16 + quad * 4 + r;
                            int gcol = colbase + nt * 16 + l15;
                            if (grow == gcol) { eA = 0.f; eT = 0.f; }
                        }
                        float e = eA + eT;
                        sP[mt][r] += e;
                        if (nt == 0) cp0 += e; else cp1 += e;
                    }

            if (ti != tj) {   // col sums -> P[tj cols] (symmetry transpose)
                cp0 += __shfl_xor(cp0, 16, 64); cp0 += __shfl_xor(cp0, 32, 64);
                cp1 += __shfl_xor(cp1, 16, 64); cp1 += __shfl_xor(cp1, 32, 64);
                if (quad == 0) {
                    atomicAdd(&P[colbase + l15],      cp0);
                    atomicAdd(&P[colbase + 16 + l15], cp1);
                }
            }
        }

        // row sums -> P[ti rows]
#pragma unroll
        for (int mt = 0; mt < 2; mt++)
#pragma unroll
            for (int r = 0; r < 4; r++) {
                float p = sP[mt][r];
                p += __shfl_xor(p, 1, 64); p += __shfl_xor(p, 2, 64);
                p += __shfl_xor(p, 4, 64); p += __shfl_xor(p, 8, 64);
                if (l15 == 0)
                    atomicAdd(&P[r0w + mt * 16 + quad * 4 + r], p);
            }
    } else {
        // ---------------- X-pass: at full sweep (round-3 verified) ----------
        const int xb = b - NS;
        const int rb = xb & 63;
        const int cs = xb >> 6;
        const int r0w = rb * 128 + wave * 32;

        bf16x8 aAu[2][4];
#pragma unroll
        for (int mt = 0; mt < 2; mt++) {
            int row = r0w + mt * 16 + l15;
            const unsigned short* pa = bau + row * DIM + quad * 8;
#pragma unroll
            for (int k = 0; k < 4; k++)
                aAu[mt][k] = *reinterpret_cast<const bf16x8*>(pa + k * 32);
        }

        float sN[2][4] = {{0.f,0.f,0.f,0.f},{0.f,0.f,0.f,0.f}};

        for (int ct = 0; ct < 16; ct++) {
            const int colbase = cs * 512 + ct * 32;
            __syncthreads();
#pragma unroll
            for (int j = 0; j < 2; j++) {
                const int f  = wave * 2 + j;     // 0..7
                const int nt = f >> 2;
                const int k  = f & 3;
                const char* gb = (const char*)btp
                               + ((size_t)(colbase + nt * 16) << 8) + (k << 6);
                GLD16(gb + laneoff, lds + (f << 9));
            }
            __syncthreads();

            bf16x8 bT[2][4];
#pragma unroll
            for (int nt = 0; nt < 2; nt++)
#pragma unroll
                for (int k = 0; k < 4; k++)
                    bT[nt][k] = *reinterpret_cast<const bf16x8*>(
                        lds + ((nt * 4 + k) << 9) + lane * 8);

            f32x4 accX[2][2];
#pragma unroll
            for (int mt = 0; mt < 2; mt++)
#pragma unroll
                for (int nt = 0; nt < 2; nt++)
                    accX[mt][nt] = f32x4{-C2, -C2, -C2, -C2};
#pragma unroll
            for (int k = 0; k < 4; k++)
#pragma unroll
                for (int mt = 0; mt < 2; mt++) {
                    accX[mt][0] = __builtin_amdgcn_mfma_f32_16x16x32_bf16(
                        aAu[mt][k], bT[0][k], accX[mt][0], 0, 0, 0);
                    accX[mt][1] = __builtin_amdgcn_mfma_f32_16x16x32_bf16(
                        aAu[mt][k], bT[1][k], accX[mt][1], 0, 0, 0);
                }

            const bool dg = (colbase < r0w + 32) && (colbase + 32 > r0w);
#pragma unroll
            for (int mt = 0; mt < 2; mt++)
#pragma unroll
                for (int nt = 0; nt < 2; nt++)
#pragma unroll
                    for (int r = 0; r < 4; r++) {
                        float e = __builtin_amdgcn_exp2f(accX[mt][nt][r]);
                        if (dg) {
                            int grow = r0w + mt * 16 + quad * 4 + r;
                            int gcol = colbase + nt * 16 + l15;
                            if (grow == gcol) e = 0.f;
                        }
                        sN[mt][r] += e;
                    }
        }

#pragma unroll
        for (int mt = 0; mt < 2; mt++)
#pragma unroll
            for (int r = 0; r < 4; r++) {
                float ng = sN[mt][r];
                ng += __shfl_xor(ng, 1, 64); ng += __shfl_xor(ng, 2, 64);
                ng += __shfl_xor(ng, 4, 64); ng += __shfl_xor(ng, 8, 64);
                if (l15 == 0)
                    atomicAdd(&Ng[r0w + mt * 16 + quad * 4 + r], ng);
            }
    }

    // ---------------- finale: last block reduces the scalar ----------------
    __syncthreads();
    if (tid == 0) {
        __threadfence();
        unsigned t = atomicAdd(done, 1u);
        lastflag = (t == (unsigned)(gridDim.x - 1)) ? 1 : 0;
    }
    __syncthreads();
    if (lastflag) {
        __threadfence();   // acquire
        float ssum = 0.f, psum = 0.f;
        for (int i = tid; i < N_ROWS; i += 256) {
            float p  = __hip_atomic_load(&P[i],  __ATOMIC_RELAXED,
                                         __HIP_MEMORY_SCOPE_AGENT);
            float ng = __hip_atomic_load(&Ng[i], __ATOMIC_RELAXED,
                                         __HIP_MEMORY_SCOPE_AGENT);
            ssum += LN2 * (__builtin_amdgcn_logf(ng) -
                           __builtin_amdgcn_logf(p)) + 2.0f * dd[i];
        }
        for (int i = tid; i < 1024; i += 256) psum += ptpart[i];
        for (int m = 1; m < 64; m <<= 1) {
            ssum += __shfl_xor(ssum, m, 64);
            psum += __shfl_xor(psum, m, 64);
        }
        if (lane == 0) { red[wave] = ssum; red2[wave] = psum; }
        __syncthreads();
        if (tid == 0) {
            float S  = red[0] + red[1] + red[2] + red[3];
            float Pt = red2[0] + red2[1] + red2[2] + red2[3];
            out[0] = (Pt / (float)N_ROWS + S) / (float)(N_ROWS + 2);
        }
    }
}

extern "C" void kernel_launch(void* const* d_in, const int* in_sizes, int n_in,
                              void* d_out, int out_size, void* d_ws, size_t ws_size,
                              hipStream_t stream) {
    const float* zau = (const float*)d_in[0];
    const float* ztp = (const float*)d_in[1];
    const float* fc  = (const float*)d_in[2];
    // d_in[3] = labels (unused by the math)
    float* out = (float*)d_out;

    char* ws = (char*)d_ws;
    unsigned short* bau = (unsigned short*)(ws);
    unsigned short* btp = (unsigned short*)(ws + 2097152);
    float*    P      = (float*)(ws + 4194304);
    float*    Ng     = (float*)(ws + 4227072);
    float*    dd     = (float*)(ws + 4259840);
    float*    ptpart = (float*)(ws + 4292608);
    unsigned* done   = (unsigned*)(ws + 4296704);

    prep_kernel<<<dim3(1024), dim3(256), 0, stream>>>(
        zau, ztp, fc, bau, btp, P, Ng, dd, ptpart, done);
    score_kernel<<<dim3(NS + NX), dim3(256), 0, stream>>>(
        bau, btp, P, Ng, dd, ptpart, done, out);
}